// Round 1
// baseline (79.652 us; speedup 1.0000x reference)
//
#include <hip/hip_runtime.h>
#include <hip/hip_bf16.h>

typedef __attribute__((ext_vector_type(8))) short bf8_t;   // 8 x bf16 (4 VGPRs)
typedef __attribute__((ext_vector_type(4))) float f4_t;    // 4 x f32 acc

static __device__ __forceinline__ short f2bf(float f) {
    union { float f; unsigned u; } v; v.f = f;
    unsigned r = v.u + 0x7fffu + ((v.u >> 16) & 1u);   // round-to-nearest-even
    return (short)(r >> 16);
}
static __device__ __forceinline__ float bf2f(short s) {
    union { unsigned u; float f; } v;
    v.u = ((unsigned)(unsigned short)s) << 16;
    return v.f;
}

// ---------------------------------------------------------------------------
// K0: P [1024 k][64 n] fp32  ->  Pt [64 n][1024 k] bf16
// ---------------------------------------------------------------------------
__global__ void __launch_bounds__(256)
transpose_p(const float* __restrict__ P, short* __restrict__ Pt) {
    int idx = blockIdx.x * 256 + threadIdx.x;   // 0..65535
    int n = idx >> 10, k = idx & 1023;
    Pt[idx] = f2bf(P[k * 64 + n]);
}

// ---------------------------------------------------------------------------
// K1: t = x @ P computed as D = P^T (A, 64x1024) x x^T (B, 1024x4096).
// One block per 16-sample n-tile; 4 waves split K (256 each), LDS-reduce.
// Epilogue (wave 0): round t to bf16, store [4096][64], and store fp32 row
// norms computed FROM THE ROUNDED bf16 values (diagonal consistency with K2).
// A-frag: lane holds A[m=lane&15][k=quad*8+j] -> contiguous 16B of Pt row.
// B-frag: lane holds B[k=quad*8+j][n=lane&15] -> contiguous 32B of x row, cast.
// C/D:    col = lane&15 (= sample n), row = quad*4+reg (= rank m).
// ---------------------------------------------------------------------------
__global__ void __launch_bounds__(256)
proj_kernel(const float* __restrict__ x, const short* __restrict__ Pt,
            short* __restrict__ t, float* __restrict__ norms) {
    const int w    = threadIdx.x >> 6;     // wave id 0..3 (K-split)
    const int lane = threadIdx.x & 63;
    const int nr   = lane & 15;            // sample within tile / rank m-lane
    const int quad = lane >> 4;
    const int row  = blockIdx.x * 16 + nr; // global sample row

    f4_t acc[4];
    #pragma unroll
    for (int mt = 0; mt < 4; mt++) acc[mt] = f4_t{0.f, 0.f, 0.f, 0.f};

    const float* xr = x + (size_t)row * 1024;
    #pragma unroll
    for (int kt = 0; kt < 8; kt++) {
        const int kb = w * 256 + kt * 32 + quad * 8;
        f4_t x0 = *(const f4_t*)(xr + kb);
        f4_t x1 = *(const f4_t*)(xr + kb + 4);
        bf8_t bfr;
        bfr[0] = f2bf(x0[0]); bfr[1] = f2bf(x0[1]);
        bfr[2] = f2bf(x0[2]); bfr[3] = f2bf(x0[3]);
        bfr[4] = f2bf(x1[0]); bfr[5] = f2bf(x1[1]);
        bfr[6] = f2bf(x1[2]); bfr[7] = f2bf(x1[3]);
        #pragma unroll
        for (int mt = 0; mt < 4; mt++) {
            bf8_t afr = *(const bf8_t*)(Pt + (size_t)(mt * 16 + nr) * 1024 + kb);
            acc[mt] = __builtin_amdgcn_mfma_f32_16x16x32_bf16(afr, bfr, acc[mt], 0, 0, 0);
        }
    }

    // cross-wave (K-split) reduction through LDS
    __shared__ float red[3][16][64];
    if (w > 0) {
        #pragma unroll
        for (int mt = 0; mt < 4; mt++)
            #pragma unroll
            for (int r = 0; r < 4; r++)
                red[w - 1][mt * 4 + r][lane] = acc[mt][r];
    }
    __syncthreads();

    if (w == 0) {
        float nrm = 0.f;
        #pragma unroll
        for (int mt = 0; mt < 4; mt++) {
            float v0 = acc[mt][0] + red[0][mt*4+0][lane] + red[1][mt*4+0][lane] + red[2][mt*4+0][lane];
            float v1 = acc[mt][1] + red[0][mt*4+1][lane] + red[1][mt*4+1][lane] + red[2][mt*4+1][lane];
            float v2 = acc[mt][2] + red[0][mt*4+2][lane] + red[1][mt*4+2][lane] + red[2][mt*4+2][lane];
            float v3 = acc[mt][3] + red[0][mt*4+3][lane] + red[1][mt*4+3][lane] + red[2][mt*4+3][lane];
            short s0 = f2bf(v0), s1 = f2bf(v1), s2 = f2bf(v2), s3 = f2bf(v3);
            float b0 = bf2f(s0), b1 = bf2f(s1), b2 = bf2f(s2), b3 = bf2f(s3);
            nrm += b0*b0 + b1*b1 + b2*b2 + b3*b3;
            short4 sv; sv.x = s0; sv.y = s1; sv.z = s2; sv.w = s3;
            // lane holds t[row][m] for m = mt*16 + quad*4 + {0..3}
            *(short4*)(t + (size_t)row * 64 + mt * 16 + quad * 4) = sv;
        }
        // nrm covers m in quad's 16-element set; reduce across quads
        nrm += __shfl_xor(nrm, 16);
        nrm += __shfl_xor(nrm, 32);
        if (quad == 0) norms[row] = nrm;
    }
}

// ---------------------------------------------------------------------------
// K2: out[b,i,j] = n_i + n_j - 2 * sum_k t[b,i,k]*t[b,j,k]
// Grid (64, 4): 8x8 tiles of 128x128 per batch. 4 waves per block (2x2),
// each wave computes 64x64 = 4x4 MFMA tiles, K=64 in two 16x16x32 steps.
// Fragments loaded directly from global bf16 t (16B contiguous per lane).
// ---------------------------------------------------------------------------
__global__ void __launch_bounds__(256)
pairwise_kernel(const short* __restrict__ t, const float* __restrict__ norms,
                float* __restrict__ out) {
    const int b    = blockIdx.y;
    const int ti   = blockIdx.x >> 3;
    const int tj   = blockIdx.x & 7;
    const int w    = threadIdx.x >> 6;
    const int lane = threadIdx.x & 63;
    const int wy   = w >> 1, wx = w & 1;
    const int i0   = ti * 128 + wy * 64;
    const int j0   = tj * 128 + wx * 64;
    const int nr   = lane & 15, quad = lane >> 4;

    __shared__ float ni[128], nj[128];
    if (threadIdx.x < 128) ni[threadIdx.x]       = norms[b * 1024 + ti * 128 + threadIdx.x];
    else                   nj[threadIdx.x - 128] = norms[b * 1024 + tj * 128 + (threadIdx.x - 128)];
    __syncthreads();

    const short* tb = t + (size_t)b * 1024 * 64;

    f4_t acc[4][4];
    #pragma unroll
    for (int ia = 0; ia < 4; ia++)
        #pragma unroll
        for (int jb = 0; jb < 4; jb++) acc[ia][jb] = f4_t{0.f, 0.f, 0.f, 0.f};

    #pragma unroll
    for (int kt = 0; kt < 2; kt++) {
        const int kb = kt * 32 + quad * 8;
        bf8_t A[4], B[4];
        #pragma unroll
        for (int ia = 0; ia < 4; ia++)
            A[ia] = *(const bf8_t*)(tb + (size_t)(i0 + ia * 16 + nr) * 64 + kb);
        #pragma unroll
        for (int jb = 0; jb < 4; jb++)
            B[jb] = *(const bf8_t*)(tb + (size_t)(j0 + jb * 16 + nr) * 64 + kb);
        #pragma unroll
        for (int ia = 0; ia < 4; ia++)
            #pragma unroll
            for (int jb = 0; jb < 4; jb++)
                acc[ia][jb] = __builtin_amdgcn_mfma_f32_16x16x32_bf16(A[ia], B[jb], acc[ia][jb], 0, 0, 0);
    }

    // epilogue: out = n_i + n_j - 2*G ;  D row = quad*4+r (i), col = nr (j)
    #pragma unroll
    for (int ia = 0; ia < 4; ia++) {
        #pragma unroll
        for (int r = 0; r < 4; r++) {
            const int irow = i0 + ia * 16 + quad * 4 + r;
            const float niv = ni[wy * 64 + ia * 16 + quad * 4 + r];
            float* orow = out + ((size_t)b * 1024 + irow) * 1024 + j0 + nr;
            #pragma unroll
            for (int jb = 0; jb < 4; jb++) {
                float v = niv + nj[wx * 64 + jb * 16 + nr] - 2.f * acc[ia][jb][r];
                orow[jb * 16] = v;
            }
        }
    }
}

// ---------------------------------------------------------------------------
extern "C" void kernel_launch(void* const* d_in, const int* in_sizes, int n_in,
                              void* d_out, int out_size, void* d_ws, size_t ws_size,
                              hipStream_t stream) {
    const float* x = (const float*)d_in[0];   // [4,1024,1024]
    const float* P = (const float*)d_in[1];   // [1024,64]
    float* out = (float*)d_out;               // [4,1024,1024]

    // workspace layout: Pt (128 KB bf16) | t (512 KB bf16) | norms (16 KB f32)
    short* Pt    = (short*)d_ws;
    short* t     = (short*)d_ws + 65536;
    float* norms = (float*)((char*)d_ws + (128 + 512) * 1024);

    transpose_p<<<256, 256, 0, stream>>>(P, Pt);
    proj_kernel<<<256, 256, 0, stream>>>(x, Pt, t, norms);
    dim3 g2(64, 4);
    pairwise_kernel<<<g2, 256, 0, stream>>>(t, norms, out);
}